// Round 4
// baseline (254.561 us; speedup 1.0000x reference)
//
#include <hip/hip_runtime.h>
#include <cstdint>
#include <cstddef>

// Problem constants
#define NB 1024        // batch of triples
#define NE 50000       // entities
#define DCOL 512       // dimension D
#define ATTN_C 8       // cores

static const size_t SCORES_OFF = (size_t)NB * NE;        // 51,200,000
static const size_t F1_OFF = SCORES_OFF + 0;
static const size_t F2_OFF = SCORES_OFF + 1;
static const size_t F3_OFF = SCORES_OFF + 2;
static const size_t ATTN_OFF = SCORES_OFF + 3;

typedef float f32x4 __attribute__((ext_vector_type(4)));
typedef short s16x8 __attribute__((ext_vector_type(8)));

__device__ __forceinline__ unsigned short f2bf(float f) {
  union { float f; uint32_t u; } x; x.f = f;
  uint32_t u = x.u;
  uint32_t r = (u + 0x7fffu + ((u >> 16) & 1u)) >> 16;  // RNE
  return (unsigned short)r;
}

__device__ __forceinline__ void gload16(const void* g, void* l) {
  __builtin_amdgcn_global_load_lds(
      (const __attribute__((address_space(1))) uint32_t*)g,
      (__attribute__((address_space(3))) uint32_t*)l, 16, 0, 0);
}

// ---------------------------------------------------------------------------
// K1 (fused prep): blocks 0..1023 = gather h,r -> HR bf16 [NB][1024] and
// n1[b] = |h|^2+|r|^2+|t|^2; blocks 1024..1535 = transpose W1 -> bf16.
// ---------------------------------------------------------------------------
__global__ __launch_bounds__(256)
void prep(const int* __restrict__ heads, const int* __restrict__ rels,
          const int* __restrict__ tails, const float* __restrict__ ew,
          const float* __restrict__ rw, const float* __restrict__ w1,
          unsigned short* __restrict__ hrb, unsigned short* __restrict__ w1t,
          float* __restrict__ n1) {
  int tid = threadIdx.x;
  if (blockIdx.x < NB) {
    int b = blockIdx.x;
    const float* h = ew + (size_t)heads[b] * DCOL;
    const float* r = rw + (size_t)rels[b] * DCOL;
    const float* t = ew + (size_t)tails[b] * DCOL;
    float acc = 0.f;
    #pragma unroll
    for (int it = 0; it < 2; ++it) {
      int d = it * 256 + tid;
      float hv = h[d], rv = r[d], tv = t[d];
      hrb[(size_t)b * 1024 + d] = f2bf(hv);
      hrb[(size_t)b * 1024 + DCOL + d] = f2bf(rv);
      acc += hv * hv + rv * rv + tv * tv;
    }
    __shared__ float red[256];
    red[tid] = acc; __syncthreads();
    for (int s = 128; s > 0; s >>= 1) {
      if (tid < s) red[tid] += red[tid + s];
      __syncthreads();
    }
    if (tid == 0) n1[b] = red[0];
  } else {
    int tb = blockIdx.x - NB;          // 0..511
    int nb = (tb & 15) * 32, kb = (tb >> 4) * 32;
    __shared__ float tile[32][33];
    int tx = tid & 31, ty = tid >> 5;  // ty 0..7
    #pragma unroll
    for (int rr = 0; rr < 32; rr += 8)
      tile[ty + rr][tx] = w1[(size_t)(kb + ty + rr) * 512 + nb + tx];
    __syncthreads();
    #pragma unroll
    for (int rr = 0; rr < 32; rr += 8)
      w1t[(size_t)(nb + ty + rr) * 1024 + kb + tx] = f2bf(tile[tx][ty + rr]);
  }
}

// ---------------------------------------------------------------------------
// K2/K4: NT GEMM -> fp32.  C[M,Nc] = A[M,K] * B[N,K]^T  (+bias, relu)
// Tile (32*FR)^2, BK=64, 4 waves (2x2), mfma_f32_16x16x32_bf16.
// A: bf16, global_load_lds width-16 with XOR-chunk swizzle.
// B: bf16 gload (BF32=0) or fp32 reg-staged + converted to bf16 (BF32=1,
//    row index clamped to NrowsB-1; excess cols masked by gn<Nc).
// Grid: x = M-tiles (few), y = N-tiles (many) -> blocks sharing a B-tile are
// dispatch-adjacent (B read from HBM once).
// ---------------------------------------------------------------------------
template <int EPI, int FR, int BF32>
__global__ __launch_bounds__(256, 2)
void gemm_nt(const unsigned short* __restrict__ A,
             const unsigned short* __restrict__ Bb,
             const float* __restrict__ Bf,
             float* __restrict__ C, const float* __restrict__ bias,
             int M, int N, int K, int Nc, int NrowsB) {
  constexpr int BM = FR * 32;            // tile size
  constexpr int SMEM_A = BM * 128;       // bytes per operand tile
  __shared__ __align__(16) uint8_t smem[2 * SMEM_A];
  const int tid = threadIdx.x;
  const int lane = tid & 63;
  const int wv = tid >> 6;
  const int wm = wv >> 1, wn = wv & 1;
  const int m0 = blockIdx.x * BM;
  const int n0 = blockIdx.y * BM;
  const int rbytes = K * 2;

  f32x4 acc[FR][FR];
  #pragma unroll
  for (int i = 0; i < FR; ++i)
    #pragma unroll
    for (int j = 0; j < FR; ++j) acc[i][j] = (f32x4){0.f, 0.f, 0.f, 0.f};

  const int srow = lane >> 3;   // row within 8-row chunk
  const int scol = lane & 7;    // dest 16B unit within row
  const int nkt = K >> 6;       // K / 64

  for (int kt = 0; kt < nkt; ++kt) {
    #pragma unroll
    for (int j = 0; j < FR; ++j) {
      int chunk = wv * FR + j;
      int r = chunk * 8 + srow;
      int c = scol ^ (r & 7);
      const uint8_t* ga = (const uint8_t*)A + (size_t)(m0 + r) * rbytes + kt * 128 + c * 16;
      gload16(ga, &smem[chunk * 1024]);
      if (BF32) {
        int rn = n0 + r; rn = rn < NrowsB ? rn : NrowsB - 1;
        const float* src = Bf + (size_t)rn * K + kt * 64 + c * 8;
        float4 v0 = *(const float4*)src;
        float4 v1 = *(const float4*)(src + 4);
        s16x8 o;
        o[0] = (short)f2bf(v0.x); o[1] = (short)f2bf(v0.y);
        o[2] = (short)f2bf(v0.z); o[3] = (short)f2bf(v0.w);
        o[4] = (short)f2bf(v1.x); o[5] = (short)f2bf(v1.y);
        o[6] = (short)f2bf(v1.z); o[7] = (short)f2bf(v1.w);
        *(s16x8*)&smem[SMEM_A + chunk * 1024 + srow * 128 + scol * 16] = o;
      } else {
        const uint8_t* gb = (const uint8_t*)Bb + (size_t)(n0 + r) * rbytes + kt * 128 + c * 16;
        gload16(gb, &smem[SMEM_A + chunk * 1024]);
      }
    }
    __syncthreads();
    #pragma unroll
    for (int kk = 0; kk < 2; ++kk) {
      s16x8 af[FR], bfr[FR];
      #pragma unroll
      for (int f = 0; f < FR; ++f) {
        int ra = wm * 16 * FR + f * 16 + (lane & 15);
        int ca = (kk * 4 + (lane >> 4)) ^ (ra & 7);
        af[f] = *(const s16x8*)&smem[ra * 128 + ca * 16];
        int rb = wn * 16 * FR + f * 16 + (lane & 15);
        int cb = (kk * 4 + (lane >> 4)) ^ (rb & 7);
        bfr[f] = *(const s16x8*)&smem[SMEM_A + rb * 128 + cb * 16];
      }
      #pragma unroll
      for (int fm = 0; fm < FR; ++fm)
        #pragma unroll
        for (int fn = 0; fn < FR; ++fn)
          acc[fm][fn] = __builtin_amdgcn_mfma_f32_16x16x32_bf16(
              af[fm], bfr[fn], acc[fm][fn], 0, 0, 0);
    }
    __syncthreads();
  }

  const int rl = lane >> 4, cl = lane & 15;
  #pragma unroll
  for (int fm = 0; fm < FR; ++fm)
    #pragma unroll
    for (int fn = 0; fn < FR; ++fn)
      #pragma unroll
      for (int j = 0; j < 4; ++j) {
        int gm = m0 + wm * 16 * FR + fm * 16 + rl * 4 + j;
        int gn = n0 + wn * 16 * FR + fn * 16 + cl;
        if (gn < Nc) {
          float v = acc[fm][fn][j];
          if (EPI) v = fmaxf(v + bias[gn], 0.f);
          C[(size_t)gm * Nc + gn] = v;
        }
      }
}

// ---------------------------------------------------------------------------
// K3: per-triple: attn logits+softmax (fused), Weff, contraction, n2.
// 256 threads: thread = (i0 = tid>>4 in 0..15, so = tid&15); each thread
// computes output rows i0 and i0+16. W1/W2/W3 interleaved in ONE float4 LDS
// array so each (u,v) iteration is a single ds_read_b128 at an immediate
// offset (base = so*16B). All register-array indices static (rule #20).
// ---------------------------------------------------------------------------
__global__ __launch_bounds__(256, 2)
void triple_core(const int* __restrict__ heads, const int* __restrict__ rels,
                 const int* __restrict__ tails, const float* __restrict__ ew,
                 const float* __restrict__ rw, const float* __restrict__ wc,
                 const float* __restrict__ hid, const float* __restrict__ w2,
                 const float* __restrict__ b2, float* __restrict__ attn_out,
                 unsigned short* __restrict__ x1b, float* __restrict__ n2) {
  __shared__ float hs[512], rs[512], ts[512];
  __shared__ __align__(16) float W123[4096][4];   // 64 KB
  __shared__ float att[8];
  __shared__ float wred[4][8];
  __shared__ float red[256];
  int b = blockIdx.x, tid = threadIdx.x;
  int lane = tid & 63, wid = tid >> 6;
  const float* hp_ = ew + (size_t)heads[b] * DCOL;
  const float* rp_ = rw + (size_t)rels[b] * DCOL;
  const float* tp_ = ew + (size_t)tails[b] * DCOL;
  float la[8] = {0, 0, 0, 0, 0, 0, 0, 0};
  #pragma unroll
  for (int it = 0; it < 2; ++it) {
    int d = it * 256 + tid;
    hs[d] = hp_[d]; rs[d] = rp_[d]; ts[d] = tp_[d];
    float hv = hid[(size_t)b * DCOL + d];
    #pragma unroll
    for (int c = 0; c < 8; ++c) la[c] = fmaf(hv, w2[d * 8 + c], la[c]);
  }
  // attention: wave reduce then cross-wave + softmax
  #pragma unroll
  for (int off = 32; off > 0; off >>= 1)
    #pragma unroll
    for (int c = 0; c < 8; ++c) la[c] += __shfl_down(la[c], off);
  if (lane == 0)
    #pragma unroll
    for (int c = 0; c < 8; ++c) wred[wid][c] = la[c];
  __syncthreads();
  if (tid == 0) {
    float lg[8];
    #pragma unroll
    for (int c = 0; c < 8; ++c)
      lg[c] = wred[0][c] + wred[1][c] + wred[2][c] + wred[3][c] + b2[c];
    float mx = lg[0];
    #pragma unroll
    for (int c = 1; c < 8; ++c) mx = fmaxf(mx, lg[c]);
    float e[8], s = 0.f;
    #pragma unroll
    for (int c = 0; c < 8; ++c) { e[c] = expf(lg[c] - mx); s += e[c]; }
    #pragma unroll
    for (int c = 0; c < 8; ++c) {
      float a = e[c] / s;
      att[c] = a;
      attn_out[(size_t)b * 8 + c] = a;
    }
  }
  __syncthreads();
  #pragma unroll
  for (int it = 0; it < 16; ++it) {
    int idx = it * 256 + tid;
    float w = 0.f;
    #pragma unroll
    for (int c = 0; c < 8; ++c) w = fmaf(att[c], wc[c * 4096 + idx], w);
    int s = idx & 15, q = (idx >> 4) & 15, p = idx >> 8;
    W123[idx][0] = w;                     // [p][q][s]
    W123[(q * 16 + s) * 16 + p][1] = w;   // [q][s][p]
    W123[(p * 16 + s) * 16 + q][2] = w;   // [p][s][q]
  }
  __syncthreads();

  const int so = tid & 15;
  const int i0 = tid >> 4, i1 = i0 + 16;
  float h0[16], r0[16], t0[16], h1[16], r1[16], t1[16];
  #pragma unroll
  for (int k = 0; k < 16; ++k) {
    h0[k] = hs[i0 * 16 + k]; r0[k] = rs[i0 * 16 + k]; t0[k] = ts[i0 * 16 + k];
    h1[k] = hs[i1 * 16 + k]; r1[k] = rs[i1 * 16 + k]; t1[k] = ts[i1 * 16 + k];
  }
  float a10 = 0.f, a20 = 0.f, a30 = 0.f, a11 = 0.f, a21 = 0.f, a31 = 0.f;
  const float4* wp = (const float4*)&W123[so][0];   // per-thread base
  #pragma unroll
  for (int u = 0; u < 16; ++u) {
    #pragma unroll
    for (int v = 0; v < 16; ++v) {
      float4 w = wp[u * 256 + v * 16];   // byte off = u*4096+v*256 (imm)
      a10 = fmaf(h0[u] * r0[v], w.x, a10);
      a20 = fmaf(r0[u] * t0[v], w.y, a20);
      a30 = fmaf(h0[u] * t0[v], w.z, a30);
      a11 = fmaf(h1[u] * r1[v], w.x, a11);
      a21 = fmaf(r1[u] * t1[v], w.y, a21);
      a31 = fmaf(h1[u] * t1[v], w.z, a31);
    }
  }
  x1b[(size_t)b * 512 + i0 * 16 + so] = f2bf(a10);
  x1b[(size_t)b * 512 + i1 * 16 + so] = f2bf(a11);
  red[tid] = a10 * a10 + a20 * a20 + a30 * a30
           + a11 * a11 + a21 * a21 + a31 * a31;
  __syncthreads();
  for (int s = 128; s > 0; s >>= 1) {
    if (tid < s) red[tid] += red[tid + s];
    __syncthreads();
  }
  if (tid == 0) n2[b] = red[0];
}

// ---------------------------------------------------------------------------
// K5: factors. factor1 = sum(n1)/B; factor2 = sum(n2)/B; factor3 geometric.
// ---------------------------------------------------------------------------
__global__ __launch_bounds__(256)
void finalize(const float* __restrict__ n1, const float* __restrict__ n2,
              const float* __restrict__ wc, float* __restrict__ out) {
  int tid = threadIdx.x;
  __shared__ float red[256];
  float a = 0.f;
  for (int i = tid; i < NB; i += 256) a += n1[i];
  red[tid] = a; __syncthreads();
  for (int s = 128; s > 0; s >>= 1) { if (tid < s) red[tid] += red[tid + s]; __syncthreads(); }
  if (tid == 0) out[F1_OFF] = red[0] / (float)NB;
  __syncthreads();
  a = 0.f;
  for (int i = tid; i < NB; i += 256) a += n2[i];
  red[tid] = a; __syncthreads();
  for (int s = 128; s > 0; s >>= 1) { if (tid < s) red[tid] += red[tid + s]; __syncthreads(); }
  if (tid == 0) out[F2_OFF] = red[0] / (float)NB;
  __syncthreads();

  // factor3: 32 lanes per core
  int c = tid >> 5, l = tid & 31;
  float tot = 0.f, cx = 0.f, cy = 0.f, cz = 0.f;
  for (int e = l; e < 4096; e += 32) {
    float w = fabsf(wc[c * 4096 + e]);
    int z = e & 15, y = (e >> 4) & 15, x = e >> 8;
    tot += w; cx += w * x; cy += w * y; cz += w * z;
  }
  #pragma unroll
  for (int off = 16; off > 0; off >>= 1) {
    tot += __shfl_down(tot, off);
    cx += __shfl_down(cx, off);
    cy += __shfl_down(cy, off);
    cz += __shfl_down(cz, off);
  }
  __shared__ float cent[8][3];
  if (l == 0) { cent[c][0] = cx / tot; cent[c][1] = cy / tot; cent[c][2] = cz / tot; }
  __syncthreads();
  if (tid == 0) {
    float f3 = 0.f;
    for (int i = 0; i < 8; ++i) {
      float mn = 1e30f;
      for (int j = 0; j < 8; ++j) {
        if (j == i) continue;
        float dx = cent[i][0] - cent[j][0];
        float dy = cent[i][1] - cent[j][1];
        float dz = cent[i][2] - cent[j][2];
        float d = sqrtf(dx * dx + dy * dy + dz * dz);
        mn = fminf(mn, d);
      }
      f3 += logf(mn + 1e-6f);
    }
    out[F3_OFF] = -f3 / 8.f;
  }
}

// ---------------------------------------------------------------------------
extern "C" void kernel_launch(void* const* d_in, const int* in_sizes, int n_in,
                              void* d_out, int out_size, void* d_ws, size_t ws_size,
                              hipStream_t stream) {
  const int* heads = (const int*)d_in[0];
  const int* rels = (const int*)d_in[1];
  const int* tails = (const int*)d_in[2];
  const float* ew = (const float*)d_in[3];
  const float* rw = (const float*)d_in[4];
  const float* wc = (const float*)d_in[5];
  const float* w1 = (const float*)d_in[6];
  const float* b1 = (const float*)d_in[7];
  const float* w2 = (const float*)d_in[8];
  const float* b2 = (const float*)d_in[9];
  float* out = (float*)d_out;

  uint8_t* ws = (uint8_t*)d_ws;
  unsigned short* hrb = (unsigned short*)ws;                       // 2 MB
  unsigned short* w1t = (unsigned short*)(ws + 2097152);           // 1 MB
  float* hid = (float*)(ws + 2097152 + 1048576);                   // 2 MB
  unsigned short* x1b = (unsigned short*)(ws + 2097152 + 1048576 + 2097152);  // 1 MB
  float* n1 = (float*)(ws + 2097152 + 1048576 + 2097152 + 1048576);
  float* n2 = n1 + NB;

  prep<<<NB + 512, 256, 0, stream>>>(heads, rels, tails, ew, rw, w1, hrb, w1t, n1);
  gemm_nt<1, 2, 0><<<dim3(16, 8), 256, 0, stream>>>(
      hrb, w1t, nullptr, hid, b1, 1024, 512, 1024, 512, 512);
  triple_core<<<NB, 256, 0, stream>>>(heads, rels, tails, ew, rw, wc,
                                      hid, w2, b2, out + ATTN_OFF, x1b, n2);
  gemm_nt<0, 4, 1><<<dim3(8, 391), 256, 0, stream>>>(
      x1b, nullptr, ew, out, nullptr, 1024, 50048, 512, NE, NE);
  finalize<<<1, 256, 0, stream>>>(n1, n2, wc, out);
}

// Round 5
// 248.425 us; speedup vs baseline: 1.0247x; 1.0247x over previous
//
#include <hip/hip_runtime.h>
#include <cstdint>
#include <cstddef>

// Problem constants
#define NB 1024        // batch of triples
#define NE 50000       // entities
#define DCOL 512       // dimension D
#define ATTN_C 8       // cores

static const size_t SCORES_OFF = (size_t)NB * NE;        // 51,200,000
static const size_t F1_OFF = SCORES_OFF + 0;
static const size_t F2_OFF = SCORES_OFF + 1;
static const size_t F3_OFF = SCORES_OFF + 2;
static const size_t ATTN_OFF = SCORES_OFF + 3;

typedef float f32x4 __attribute__((ext_vector_type(4)));
typedef short s16x8 __attribute__((ext_vector_type(8)));

__device__ __forceinline__ unsigned short f2bf(float f) {
  union { float f; uint32_t u; } x; x.f = f;
  uint32_t u = x.u;
  uint32_t r = (u + 0x7fffu + ((u >> 16) & 1u)) >> 16;  // RNE
  return (unsigned short)r;
}

__device__ __forceinline__ void gload16(const void* g, void* l) {
  __builtin_amdgcn_global_load_lds(
      (const __attribute__((address_space(1))) uint32_t*)g,
      (__attribute__((address_space(3))) uint32_t*)l, 16, 0, 0);
}

// ---------------------------------------------------------------------------
// K1 (fused prep): blocks 0..1023 = gather h,r -> HR bf16 [NB][1024] and
// n1[b] = |h|^2+|r|^2+|t|^2; blocks 1024..1535 = transpose W1 -> bf16.
// ---------------------------------------------------------------------------
__global__ __launch_bounds__(256)
void prep(const int* __restrict__ heads, const int* __restrict__ rels,
          const int* __restrict__ tails, const float* __restrict__ ew,
          const float* __restrict__ rw, const float* __restrict__ w1,
          unsigned short* __restrict__ hrb, unsigned short* __restrict__ w1t,
          float* __restrict__ n1) {
  int tid = threadIdx.x;
  if (blockIdx.x < NB) {
    int b = blockIdx.x;
    const float* h = ew + (size_t)heads[b] * DCOL;
    const float* r = rw + (size_t)rels[b] * DCOL;
    const float* t = ew + (size_t)tails[b] * DCOL;
    float acc = 0.f;
    #pragma unroll
    for (int it = 0; it < 2; ++it) {
      int d = it * 256 + tid;
      float hv = h[d], rv = r[d], tv = t[d];
      hrb[(size_t)b * 1024 + d] = f2bf(hv);
      hrb[(size_t)b * 1024 + DCOL + d] = f2bf(rv);
      acc += hv * hv + rv * rv + tv * tv;
    }
    __shared__ float red[256];
    red[tid] = acc; __syncthreads();
    for (int s = 128; s > 0; s >>= 1) {
      if (tid < s) red[tid] += red[tid + s];
      __syncthreads();
    }
    if (tid == 0) n1[b] = red[0];
  } else {
    int tb = blockIdx.x - NB;          // 0..511
    int nb = (tb & 15) * 32, kb = (tb >> 4) * 32;
    __shared__ float tile[32][33];
    int tx = tid & 31, ty = tid >> 5;  // ty 0..7
    #pragma unroll
    for (int rr = 0; rr < 32; rr += 8)
      tile[ty + rr][tx] = w1[(size_t)(kb + ty + rr) * 512 + nb + tx];
    __syncthreads();
    #pragma unroll
    for (int rr = 0; rr < 32; rr += 8)
      w1t[(size_t)(nb + ty + rr) * 1024 + kb + tx] = f2bf(tile[tx][ty + rr]);
  }
}

// ---------------------------------------------------------------------------
// K2/K4: NT GEMM -> fp32.  C[M,Nc] = A[M,K] * B[N,K]^T  (+bias, relu)
// Tile (32*FR)^2, BK=64, 4 waves (2x2), mfma_f32_16x16x32_bf16.
// Double-buffered 2-phase pipeline: issue stage(kt+1) -> compute(kt) ->
// (cvt+ds_write B regs) -> barrier.  One barrier per K-tile.
// A: bf16 via global_load_lds (width 16) with XOR-chunk swizzle.
// B: bf16 gload_lds (BF32=0) or fp32 reg-staged + cvt (BF32=1, row clamped).
// SWZ=1: XCD-ownership block swizzle — each XCD owns a contiguous run of
// N-tiles with all MT M-tiles consecutive, so each B-tile is fetched into
// exactly ONE per-XCD L2 (R4 counters: adjacent-block layout duplicated B
// across all 8 XCD L2s -> FETCH 403MB vs 104MB ideal). Needs MT*NT % 8 == 0.
// ---------------------------------------------------------------------------
template <int EPI, int FR, int BF32, int SWZ, int MT>
__global__ __launch_bounds__(256, 2)
void gemm_nt(const unsigned short* __restrict__ A,
             const unsigned short* __restrict__ Bb,
             const float* __restrict__ Bf,
             float* __restrict__ C, const float* __restrict__ bias,
             int K, int Nc, int NrowsB, int NT) {
  constexpr int BM = FR * 32;            // tile size
  constexpr int TILE = BM * 128;         // bytes per operand tile
  __shared__ __align__(16) uint8_t smem[4 * TILE];  // [buf][A|B]
  const int tid = threadIdx.x;
  const int lane = tid & 63;
  const int wv = tid >> 6;
  const int wm = wv >> 1, wn = wv & 1;

  int m_t, n_t;
  if (SWZ) {
    int xcd = blockIdx.x & 7;
    int l = blockIdx.x >> 3;
    int w = xcd * ((MT * NT) >> 3) + l;  // bijective: MT*NT % 8 == 0
    n_t = w / MT; m_t = w % MT;
  } else {
    m_t = blockIdx.x % MT; n_t = blockIdx.x / MT;
  }
  const int m0 = m_t * BM;
  const int n0 = n_t * BM;
  const int rbytes = K * 2;

  f32x4 acc[FR][FR];
  #pragma unroll
  for (int i = 0; i < FR; ++i)
    #pragma unroll
    for (int j = 0; j < FR; ++j) acc[i][j] = (f32x4){0.f, 0.f, 0.f, 0.f};

  const int srow = lane >> 3;   // row within 8-row chunk
  const int scol = lane & 7;    // dest 16B unit within row
  const int nkt = K >> 6;       // K / 64

  float4 br0[FR], br1[FR];      // fp32 B staging regs (BF32 path)

  // ---- prologue: stage tile 0 into buffer 0 ----
  #pragma unroll
  for (int j = 0; j < FR; ++j) {
    const int chunk = wv * FR + j;
    const int r = chunk * 8 + srow;
    const int c = scol ^ (r & 7);
    gload16((const uint8_t*)A + (size_t)(m0 + r) * rbytes + c * 16,
            &smem[chunk * 1024]);
    if (BF32) {
      int rn = n0 + r; rn = rn < NrowsB ? rn : NrowsB - 1;
      const float* src = Bf + (size_t)rn * K + c * 8;
      br0[j] = *(const float4*)src;
      br1[j] = *(const float4*)(src + 4);
    } else {
      gload16((const uint8_t*)Bb + (size_t)(n0 + r) * rbytes + c * 16,
              &smem[TILE + chunk * 1024]);
    }
  }
  if (BF32) {
    #pragma unroll
    for (int j = 0; j < FR; ++j) {
      const int chunk = wv * FR + j;
      s16x8 o;
      o[0] = (short)f2bf(br0[j].x); o[1] = (short)f2bf(br0[j].y);
      o[2] = (short)f2bf(br0[j].z); o[3] = (short)f2bf(br0[j].w);
      o[4] = (short)f2bf(br1[j].x); o[5] = (short)f2bf(br1[j].y);
      o[6] = (short)f2bf(br1[j].z); o[7] = (short)f2bf(br1[j].w);
      *(s16x8*)&smem[TILE + chunk * 1024 + srow * 128 + scol * 16] = o;
    }
  }
  __syncthreads();

  // ---- main loop: one barrier per K-tile ----
  int cur = 0;
  for (int kt = 0; kt < nkt; ++kt) {
    const int nxt = cur ^ 1;
    const bool hn = (kt + 1) < nkt;
    if (hn) {
      const int kn = kt + 1;
      #pragma unroll
      for (int j = 0; j < FR; ++j) {
        const int chunk = wv * FR + j;
        const int r = chunk * 8 + srow;
        const int c = scol ^ (r & 7);
        gload16((const uint8_t*)A + (size_t)(m0 + r) * rbytes + kn * 128 + c * 16,
                &smem[nxt * 2 * TILE + chunk * 1024]);
        if (BF32) {
          int rn = n0 + r; rn = rn < NrowsB ? rn : NrowsB - 1;
          const float* src = Bf + (size_t)rn * K + kn * 64 + c * 8;
          br0[j] = *(const float4*)src;
          br1[j] = *(const float4*)(src + 4);
        } else {
          gload16((const uint8_t*)Bb + (size_t)(n0 + r) * rbytes + kn * 128 + c * 16,
                  &smem[nxt * 2 * TILE + TILE + chunk * 1024]);
        }
      }
    }
    // compute on buffer `cur` (ds_read latency + MFMA hide the stage loads)
    const uint8_t* sa = &smem[cur * 2 * TILE];
    const uint8_t* sb = &smem[cur * 2 * TILE + TILE];
    #pragma unroll
    for (int kk = 0; kk < 2; ++kk) {
      s16x8 af[FR], bfv[FR];
      #pragma unroll
      for (int f = 0; f < FR; ++f) {
        const int ra = wm * 16 * FR + f * 16 + (lane & 15);
        const int ca = (kk * 4 + (lane >> 4)) ^ (ra & 7);
        af[f] = *(const s16x8*)&sa[ra * 128 + ca * 16];
        const int rb = wn * 16 * FR + f * 16 + (lane & 15);
        const int cb = (kk * 4 + (lane >> 4)) ^ (rb & 7);
        bfv[f] = *(const s16x8*)&sb[rb * 128 + cb * 16];
      }
      #pragma unroll
      for (int fm = 0; fm < FR; ++fm)
        #pragma unroll
        for (int fn = 0; fn < FR; ++fn)
          acc[fm][fn] = __builtin_amdgcn_mfma_f32_16x16x32_bf16(
              af[fm], bfv[fn], acc[fm][fn], 0, 0, 0);
    }
    if (hn && BF32) {
      #pragma unroll
      for (int j = 0; j < FR; ++j) {
        const int chunk = wv * FR + j;
        s16x8 o;
        o[0] = (short)f2bf(br0[j].x); o[1] = (short)f2bf(br0[j].y);
        o[2] = (short)f2bf(br0[j].z); o[3] = (short)f2bf(br0[j].w);
        o[4] = (short)f2bf(br1[j].x); o[5] = (short)f2bf(br1[j].y);
        o[6] = (short)f2bf(br1[j].z); o[7] = (short)f2bf(br1[j].w);
        *(s16x8*)&smem[nxt * 2 * TILE + TILE + chunk * 1024 + srow * 128 + scol * 16] = o;
      }
    }
    __syncthreads();
    cur = nxt;
  }

  const int rl = lane >> 4, cl = lane & 15;
  #pragma unroll
  for (int fm = 0; fm < FR; ++fm)
    #pragma unroll
    for (int fn = 0; fn < FR; ++fn)
      #pragma unroll
      for (int j = 0; j < 4; ++j) {
        int gm = m0 + wm * 16 * FR + fm * 16 + rl * 4 + j;
        int gn = n0 + wn * 16 * FR + fn * 16 + cl;
        if (gn < Nc) {
          float v = acc[fm][fn][j];
          if (EPI) v = fmaxf(v + bias[gn], 0.f);
          C[(size_t)gm * Nc + gn] = v;
        }
      }
}

// ---------------------------------------------------------------------------
// K3: per-triple: attn logits+softmax (fused), Weff, contraction, n2.
// 256 threads: thread = (i0 = tid>>4 in 0..15, so = tid&15); each thread
// computes output rows i0 and i0+16. W1/W2/W3 interleaved in ONE float4 LDS
// array so each (u,v) iteration is a single ds_read_b128 at an immediate
// offset (base = so*16B). All register-array indices static (rule #20).
// ---------------------------------------------------------------------------
__global__ __launch_bounds__(256, 2)
void triple_core(const int* __restrict__ heads, const int* __restrict__ rels,
                 const int* __restrict__ tails, const float* __restrict__ ew,
                 const float* __restrict__ rw, const float* __restrict__ wc,
                 const float* __restrict__ hid, const float* __restrict__ w2,
                 const float* __restrict__ b2, float* __restrict__ attn_out,
                 unsigned short* __restrict__ x1b, float* __restrict__ n2) {
  __shared__ float hs[512], rs[512], ts[512];
  __shared__ __align__(16) float W123[4096][4];   // 64 KB
  __shared__ float att[8];
  __shared__ float wred[4][8];
  __shared__ float red[256];
  int b = blockIdx.x, tid = threadIdx.x;
  int lane = tid & 63, wid = tid >> 6;
  const float* hp_ = ew + (size_t)heads[b] * DCOL;
  const float* rp_ = rw + (size_t)rels[b] * DCOL;
  const float* tp_ = ew + (size_t)tails[b] * DCOL;
  float la[8] = {0, 0, 0, 0, 0, 0, 0, 0};
  #pragma unroll
  for (int it = 0; it < 2; ++it) {
    int d = it * 256 + tid;
    hs[d] = hp_[d]; rs[d] = rp_[d]; ts[d] = tp_[d];
    float hv = hid[(size_t)b * DCOL + d];
    #pragma unroll
    for (int c = 0; c < 8; ++c) la[c] = fmaf(hv, w2[d * 8 + c], la[c]);
  }
  // attention: wave reduce then cross-wave + softmax
  #pragma unroll
  for (int off = 32; off > 0; off >>= 1)
    #pragma unroll
    for (int c = 0; c < 8; ++c) la[c] += __shfl_down(la[c], off);
  if (lane == 0)
    #pragma unroll
    for (int c = 0; c < 8; ++c) wred[wid][c] = la[c];
  __syncthreads();
  if (tid == 0) {
    float lg[8];
    #pragma unroll
    for (int c = 0; c < 8; ++c)
      lg[c] = wred[0][c] + wred[1][c] + wred[2][c] + wred[3][c] + b2[c];
    float mx = lg[0];
    #pragma unroll
    for (int c = 1; c < 8; ++c) mx = fmaxf(mx, lg[c]);
    float e[8], s = 0.f;
    #pragma unroll
    for (int c = 0; c < 8; ++c) { e[c] = expf(lg[c] - mx); s += e[c]; }
    #pragma unroll
    for (int c = 0; c < 8; ++c) {
      float a = e[c] / s;
      att[c] = a;
      attn_out[(size_t)b * 8 + c] = a;
    }
  }
  __syncthreads();
  #pragma unroll
  for (int it = 0; it < 16; ++it) {
    int idx = it * 256 + tid;
    float w = 0.f;
    #pragma unroll
    for (int c = 0; c < 8; ++c) w = fmaf(att[c], wc[c * 4096 + idx], w);
    int s = idx & 15, q = (idx >> 4) & 15, p = idx >> 8;
    W123[idx][0] = w;                     // [p][q][s]
    W123[(q * 16 + s) * 16 + p][1] = w;   // [q][s][p]
    W123[(p * 16 + s) * 16 + q][2] = w;   // [p][s][q]
  }
  __syncthreads();

  const int so = tid & 15;
  const int i0 = tid >> 4, i1 = i0 + 16;
  float h0[16], r0[16], t0[16], h1[16], r1[16], t1[16];
  #pragma unroll
  for (int k = 0; k < 16; ++k) {
    h0[k] = hs[i0 * 16 + k]; r0[k] = rs[i0 * 16 + k]; t0[k] = ts[i0 * 16 + k];
    h1[k] = hs[i1 * 16 + k]; r1[k] = rs[i1 * 16 + k]; t1[k] = ts[i1 * 16 + k];
  }
  float a10 = 0.f, a20 = 0.f, a30 = 0.f, a11 = 0.f, a21 = 0.f, a31 = 0.f;
  const float4* wp = (const float4*)&W123[so][0];   // per-thread base
  #pragma unroll
  for (int u = 0; u < 16; ++u) {
    #pragma unroll
    for (int v = 0; v < 16; ++v) {
      float4 w = wp[u * 256 + v * 16];   // byte off = u*4096+v*256 (imm)
      a10 = fmaf(h0[u] * r0[v], w.x, a10);
      a20 = fmaf(r0[u] * t0[v], w.y, a20);
      a30 = fmaf(h0[u] * t0[v], w.z, a30);
      a11 = fmaf(h1[u] * r1[v], w.x, a11);
      a21 = fmaf(r1[u] * t1[v], w.y, a21);
      a31 = fmaf(h1[u] * t1[v], w.z, a31);
    }
  }
  x1b[(size_t)b * 512 + i0 * 16 + so] = f2bf(a10);
  x1b[(size_t)b * 512 + i1 * 16 + so] = f2bf(a11);
  red[tid] = a10 * a10 + a20 * a20 + a30 * a30
           + a11 * a11 + a21 * a21 + a31 * a31;
  __syncthreads();
  for (int s = 128; s > 0; s >>= 1) {
    if (tid < s) red[tid] += red[tid + s];
    __syncthreads();
  }
  if (tid == 0) n2[b] = red[0];
}

// ---------------------------------------------------------------------------
// K5: factors. factor1 = sum(n1)/B; factor2 = sum(n2)/B; factor3 geometric.
// ---------------------------------------------------------------------------
__global__ __launch_bounds__(256)
void finalize(const float* __restrict__ n1, const float* __restrict__ n2,
              const float* __restrict__ wc, float* __restrict__ out) {
  int tid = threadIdx.x;
  __shared__ float red[256];
  float a = 0.f;
  for (int i = tid; i < NB; i += 256) a += n1[i];
  red[tid] = a; __syncthreads();
  for (int s = 128; s > 0; s >>= 1) { if (tid < s) red[tid] += red[tid + s]; __syncthreads(); }
  if (tid == 0) out[F1_OFF] = red[0] / (float)NB;
  __syncthreads();
  a = 0.f;
  for (int i = tid; i < NB; i += 256) a += n2[i];
  red[tid] = a; __syncthreads();
  for (int s = 128; s > 0; s >>= 1) { if (tid < s) red[tid] += red[tid + s]; __syncthreads(); }
  if (tid == 0) out[F2_OFF] = red[0] / (float)NB;
  __syncthreads();

  // factor3: 32 lanes per core
  int c = tid >> 5, l = tid & 31;
  float tot = 0.f, cx = 0.f, cy = 0.f, cz = 0.f;
  for (int e = l; e < 4096; e += 32) {
    float w = fabsf(wc[c * 4096 + e]);
    int z = e & 15, y = (e >> 4) & 15, x = e >> 8;
    tot += w; cx += w * x; cy += w * y; cz += w * z;
  }
  #pragma unroll
  for (int off = 16; off > 0; off >>= 1) {
    tot += __shfl_down(tot, off);
    cx += __shfl_down(cx, off);
    cy += __shfl_down(cy, off);
    cz += __shfl_down(cz, off);
  }
  __shared__ float cent[8][3];
  if (l == 0) { cent[c][0] = cx / tot; cent[c][1] = cy / tot; cent[c][2] = cz / tot; }
  __syncthreads();
  if (tid == 0) {
    float f3 = 0.f;
    for (int i = 0; i < 8; ++i) {
      float mn = 1e30f;
      for (int j = 0; j < 8; ++j) {
        if (j == i) continue;
        float dx = cent[i][0] - cent[j][0];
        float dy = cent[i][1] - cent[j][1];
        float dz = cent[i][2] - cent[j][2];
        float d = sqrtf(dx * dx + dy * dy + dz * dz);
        mn = fminf(mn, d);
      }
      f3 += logf(mn + 1e-6f);
    }
    out[F3_OFF] = -f3 / 8.f;
  }
}

// ---------------------------------------------------------------------------
extern "C" void kernel_launch(void* const* d_in, const int* in_sizes, int n_in,
                              void* d_out, int out_size, void* d_ws, size_t ws_size,
                              hipStream_t stream) {
  const int* heads = (const int*)d_in[0];
  const int* rels = (const int*)d_in[1];
  const int* tails = (const int*)d_in[2];
  const float* ew = (const float*)d_in[3];
  const float* rw = (const float*)d_in[4];
  const float* wc = (const float*)d_in[5];
  const float* w1 = (const float*)d_in[6];
  const float* b1 = (const float*)d_in[7];
  const float* w2 = (const float*)d_in[8];
  const float* b2 = (const float*)d_in[9];
  float* out = (float*)d_out;

  uint8_t* ws = (uint8_t*)d_ws;
  unsigned short* hrb = (unsigned short*)ws;                       // 2 MB
  unsigned short* w1t = (unsigned short*)(ws + 2097152);           // 1 MB
  float* hid = (float*)(ws + 2097152 + 1048576);                   // 2 MB
  unsigned short* x1b = (unsigned short*)(ws + 2097152 + 1048576 + 2097152);  // 1 MB
  float* n1 = (float*)(ws + 2097152 + 1048576 + 2097152 + 1048576);
  float* n2 = n1 + NB;

  prep<<<NB + 512, 256, 0, stream>>>(heads, rels, tails, ew, rw, w1, hrb, w1t, n1);
  // MLP GEMM: M=1024 (MT=16, BM=64), N=512 (NT=8), K=1024, bf16 B
  gemm_nt<1, 2, 0, 0, 16><<<128, 256, 0, stream>>>(
      hrb, w1t, nullptr, hid, b1, 1024, 512, 512, 8);
  triple_core<<<NB, 256, 0, stream>>>(heads, rels, tails, ew, rw, wc,
                                      hid, w2, b2, out + ATTN_OFF, x1b, n2);
  // scores GEMM: M=1024 (MT=8, BM=128), N-tiles=391, K=512, fp32 B direct
  gemm_nt<0, 4, 1, 1, 8><<<3128, 256, 0, stream>>>(
      x1b, nullptr, ew, out, nullptr, 512, NE, NE, 391);
  finalize<<<1, 256, 0, stream>>>(n1, n2, wc, out);
}

// Round 7
// 212.293 us; speedup vs baseline: 1.1991x; 1.1702x over previous
//
#include <hip/hip_runtime.h>
#include <cstdint>
#include <cstddef>

// Problem constants
#define NB 1024        // batch of triples
#define NE 50000       // entities
#define NE_PAD 50048   // padded to 391*128
#define DCOL 512       // dimension D
#define ATTN_C 8       // cores

static const size_t SCORES_OFF = (size_t)NB * NE;        // 51,200,000
static const size_t F1_OFF = SCORES_OFF + 0;
static const size_t F2_OFF = SCORES_OFF + 1;
static const size_t F3_OFF = SCORES_OFF + 2;
static const size_t ATTN_OFF = SCORES_OFF + 3;

typedef float f32x4 __attribute__((ext_vector_type(4)));
typedef short s16x8 __attribute__((ext_vector_type(8)));

__device__ __forceinline__ unsigned short f2bf(float f) {
  union { float f; uint32_t u; } x; x.f = f;
  uint32_t u = x.u;
  uint32_t r = (u + 0x7fffu + ((u >> 16) & 1u)) >> 16;  // RNE
  return (unsigned short)r;
}

__device__ __forceinline__ void gload16(const void* g, void* l) {
  __builtin_amdgcn_global_load_lds(
      (const __attribute__((address_space(1))) uint32_t*)g,
      (__attribute__((address_space(3))) uint32_t*)l, 16, 0, 0);
}

// counted vmcnt wait — N MUST equal loads-per-stage (2*FR). R6's bug:
// hardcoded vmcnt(8) was a no-op for the FR=2 instantiation (only 8
// outstanding) -> waves crossed the barrier before their loads landed.
template <int N>
__device__ __forceinline__ void waitcnt_vm() {
  static_assert(N == 0 || N == 4 || N == 8, "literal dispatch");
  if constexpr (N == 0) asm volatile("s_waitcnt vmcnt(0)" ::: "memory");
  else if constexpr (N == 4) asm volatile("s_waitcnt vmcnt(4)" ::: "memory");
  else if constexpr (N == 8) asm volatile("s_waitcnt vmcnt(8)" ::: "memory");
}

// ---------------------------------------------------------------------------
// K1 (fused prep): blocks [0,1024) = gather h,r -> HR bf16 + n1;
// blocks [1024,1536) = transpose W1 -> bf16; blocks [1536,3584) = grid-stride
// convert entity_w fp32 -> bf16 padded (B operand of the scores GEMM).
// ---------------------------------------------------------------------------
__global__ __launch_bounds__(256)
void prep(const int* __restrict__ heads, const int* __restrict__ rels,
          const int* __restrict__ tails, const float* __restrict__ ew,
          const float* __restrict__ rw, const float* __restrict__ w1,
          unsigned short* __restrict__ hrb, unsigned short* __restrict__ w1t,
          unsigned short* __restrict__ ewb, float* __restrict__ n1) {
  int tid = threadIdx.x;
  if (blockIdx.x < NB) {
    int b = blockIdx.x;
    const float* h = ew + (size_t)heads[b] * DCOL;
    const float* r = rw + (size_t)rels[b] * DCOL;
    const float* t = ew + (size_t)tails[b] * DCOL;
    float acc = 0.f;
    #pragma unroll
    for (int it = 0; it < 2; ++it) {
      int d = it * 256 + tid;
      float hv = h[d], rv = r[d], tv = t[d];
      hrb[(size_t)b * 1024 + d] = f2bf(hv);
      hrb[(size_t)b * 1024 + DCOL + d] = f2bf(rv);
      acc += hv * hv + rv * rv + tv * tv;
    }
    __shared__ float red[256];
    red[tid] = acc; __syncthreads();
    for (int s = 128; s > 0; s >>= 1) {
      if (tid < s) red[tid] += red[tid + s];
      __syncthreads();
    }
    if (tid == 0) n1[b] = red[0];
  } else if (blockIdx.x < NB + 512) {
    int tb = blockIdx.x - NB;          // 0..511
    int nb = (tb & 15) * 32, kb = (tb >> 4) * 32;
    __shared__ float tile[32][33];
    int tx = tid & 31, ty = tid >> 5;  // ty 0..7
    #pragma unroll
    for (int rr = 0; rr < 32; rr += 8)
      tile[ty + rr][tx] = w1[(size_t)(kb + ty + rr) * 512 + nb + tx];
    __syncthreads();
    #pragma unroll
    for (int rr = 0; rr < 32; rr += 8)
      w1t[(size_t)(nb + ty + rr) * 1024 + kb + tx] = f2bf(tile[tx][ty + rr]);
  } else {
    const int n4valid = NE * DCOL / 4;        // 6,400,000
    const int n4tot = NE_PAD * DCOL / 4;      // 6,406,144
    int i = (blockIdx.x - NB - 512) * 256 + tid;
    const int stride = 2048 * 256;
    for (; i < n4tot; i += stride) {
      float x = 0.f, y = 0.f, z = 0.f, w = 0.f;
      if (i < n4valid) {
        float4 v = ((const float4*)ew)[i];
        x = v.x; y = v.y; z = v.z; w = v.w;
      }
      union { unsigned short u[4]; uint2 v2; } o;
      o.u[0] = f2bf(x); o.u[1] = f2bf(y); o.u[2] = f2bf(z); o.u[3] = f2bf(w);
      ((uint2*)ewb)[i] = o.v2;
    }
  }
}

// ---------------------------------------------------------------------------
// K2/K4: NT GEMM bf16 -> fp32.  C[M,Nc] = A[M,K] * B[N,K]^T  (+bias, relu)
// Tile (32*FR)^2, BK=64, 4 waves (2x2), mfma_f32_16x16x32_bf16, both operands
// staged via global_load_lds (width 16) with XOR-chunk source swizzle.
// COUNTED-VMCNT PIPELINE (T4): raw s_barrier + s_waitcnt vmcnt(2*FR) -- the
// next tile's loads stay in flight ACROSS barriers (never drain to 0 in the
// main loop). stage(kt+2) issued after the compute-barrier into the freed
// buffer. sched_barrier(0) fences around the handshake (rule #18).
// SWZ=1: XCD-ownership swizzle (bijective, MT*NT%8==0) -> each B-tile lives
// in exactly one per-XCD L2 (R5: FETCH 403->71MB).
// ---------------------------------------------------------------------------
template <int EPI, int FR, int SWZ, int MT>
__global__ __launch_bounds__(256, 2)
void gemm_nt(const unsigned short* __restrict__ A,
             const unsigned short* __restrict__ B,
             float* __restrict__ C, const float* __restrict__ bias,
             int K, int Nc, int NT) {
  constexpr int BM = FR * 32;            // tile size
  constexpr int TILE = BM * 128;         // bytes per operand tile (BK=64)
  __shared__ __align__(16) uint8_t smem[4 * TILE];  // [buf][A|B]
  const int tid = threadIdx.x;
  const int lane = tid & 63;
  const int wv = tid >> 6;
  const int wm = wv >> 1, wn = wv & 1;

  int m_t, n_t;
  if (SWZ) {
    int xcd = blockIdx.x & 7;
    int l = blockIdx.x >> 3;
    int w = xcd * ((MT * NT) >> 3) + l;  // bijective: MT*NT % 8 == 0
    n_t = w / MT; m_t = w % MT;
  } else {
    m_t = blockIdx.x % MT; n_t = blockIdx.x / MT;
  }
  const int m0 = m_t * BM;
  const int n0 = n_t * BM;
  const int rbytes = K * 2;

  f32x4 acc[FR][FR];
  #pragma unroll
  for (int i = 0; i < FR; ++i)
    #pragma unroll
    for (int j = 0; j < FR; ++j) acc[i][j] = (f32x4){0.f, 0.f, 0.f, 0.f};

  const int srow = lane >> 3;   // row within 8-row chunk
  const int scol = lane & 7;    // dest 16B unit within row
  const int nkt = K >> 6;       // K / 64

  // stage K-tile kt into buffer buf: 2*FR gload_lds per wave (A + B)
  auto stage = [&](int kt, int buf) {
    #pragma unroll
    for (int j = 0; j < FR; ++j) {
      const int chunk = wv * FR + j;
      const int r = chunk * 8 + srow;
      const int c = scol ^ (r & 7);
      gload16((const uint8_t*)A + (size_t)(m0 + r) * rbytes + kt * 128 + c * 16,
              &smem[buf * 2 * TILE + chunk * 1024]);
      gload16((const uint8_t*)B + (size_t)(n0 + r) * rbytes + kt * 128 + c * 16,
              &smem[buf * 2 * TILE + TILE + chunk * 1024]);
    }
  };
  auto compute = [&](int buf) {
    const uint8_t* sa = &smem[buf * 2 * TILE];
    const uint8_t* sb = sa + TILE;
    #pragma unroll
    for (int kk = 0; kk < 2; ++kk) {
      s16x8 af[FR], bfv[FR];
      #pragma unroll
      for (int f = 0; f < FR; ++f) {
        const int ra = wm * 16 * FR + f * 16 + (lane & 15);
        const int ca = (kk * 4 + (lane >> 4)) ^ (ra & 7);
        af[f] = *(const s16x8*)&sa[ra * 128 + ca * 16];
        const int rb = wn * 16 * FR + f * 16 + (lane & 15);
        const int cb = (kk * 4 + (lane >> 4)) ^ (rb & 7);
        bfv[f] = *(const s16x8*)&sb[rb * 128 + cb * 16];
      }
      #pragma unroll
      for (int fm = 0; fm < FR; ++fm)
        #pragma unroll
        for (int fn = 0; fn < FR; ++fn)
          acc[fm][fn] = __builtin_amdgcn_mfma_f32_16x16x32_bf16(
              af[fm], bfv[fn], acc[fm][fn], 0, 0, 0);
    }
  };

  // prologue: two tiles in flight (4*FR outstanding loads/wave)
  stage(0, 0);
  stage(1, 1);
  // main loop: wait until only the NEXT tile's 2*FR loads remain in flight
  for (int kt = 0; kt < nkt - 1; ++kt) {
    const int cur = kt & 1;
    waitcnt_vm<2 * FR>();
    __builtin_amdgcn_sched_barrier(0);
    __builtin_amdgcn_s_barrier();          // all waves: buf[cur] ready
    __builtin_amdgcn_sched_barrier(0);
    compute(cur);
    __builtin_amdgcn_sched_barrier(0);
    __builtin_amdgcn_s_barrier();          // all waves done reading buf[cur]
    __builtin_amdgcn_sched_barrier(0);
    if (kt + 2 < nkt) stage(kt + 2, cur);  // refill freed buffer, stays in flight
  }
  // peeled last tile: drain fully
  waitcnt_vm<0>();
  __builtin_amdgcn_sched_barrier(0);
  __builtin_amdgcn_s_barrier();
  __builtin_amdgcn_sched_barrier(0);
  compute((nkt - 1) & 1);

  const int rl = lane >> 4, cl = lane & 15;
  #pragma unroll
  for (int fm = 0; fm < FR; ++fm)
    #pragma unroll
    for (int fn = 0; fn < FR; ++fn)
      #pragma unroll
      for (int j = 0; j < 4; ++j) {
        int gm = m0 + wm * 16 * FR + fm * 16 + rl * 4 + j;
        int gn = n0 + wn * 16 * FR + fn * 16 + cl;
        if (gn < Nc) {
          float v = acc[fm][fn][j];
          if (EPI) v = fmaxf(v + bias[gn], 0.f);
          C[(size_t)gm * Nc + gn] = v;
        }
      }
}

// ---------------------------------------------------------------------------
// K3: per-triple: attn logits+softmax (fused), Weff, contraction, n2.
// 256 threads: thread = (i0 = tid>>4 in 0..15, so = tid&15); each thread
// computes output rows i0 and i0+16. W1/W2/W3 interleaved in ONE float4 LDS
// array so each (u,v) iteration is a single ds_read_b128 at an immediate
// offset (base = so*16B). All register-array indices static (rule #20).
// ---------------------------------------------------------------------------
__global__ __launch_bounds__(256, 2)
void triple_core(const int* __restrict__ heads, const int* __restrict__ rels,
                 const int* __restrict__ tails, const float* __restrict__ ew,
                 const float* __restrict__ rw, const float* __restrict__ wc,
                 const float* __restrict__ hid, const float* __restrict__ w2,
                 const float* __restrict__ b2, float* __restrict__ attn_out,
                 unsigned short* __restrict__ x1b, float* __restrict__ n2) {
  __shared__ float hs[512], rs[512], ts[512];
  __shared__ __align__(16) float W123[4096][4];   // 64 KB
  __shared__ float att[8];
  __shared__ float wred[4][8];
  __shared__ float red[256];
  int b = blockIdx.x, tid = threadIdx.x;
  int lane = tid & 63, wid = tid >> 6;
  const float* hp_ = ew + (size_t)heads[b] * DCOL;
  const float* rp_ = rw + (size_t)rels[b] * DCOL;
  const float* tp_ = ew + (size_t)tails[b] * DCOL;
  float la[8] = {0, 0, 0, 0, 0, 0, 0, 0};
  #pragma unroll
  for (int it = 0; it < 2; ++it) {
    int d = it * 256 + tid;
    hs[d] = hp_[d]; rs[d] = rp_[d]; ts[d] = tp_[d];
    float hv = hid[(size_t)b * DCOL + d];
    #pragma unroll
    for (int c = 0; c < 8; ++c) la[c] = fmaf(hv, w2[d * 8 + c], la[c]);
  }
  // attention: wave reduce then cross-wave + softmax
  #pragma unroll
  for (int off = 32; off > 0; off >>= 1)
    #pragma unroll
    for (int c = 0; c < 8; ++c) la[c] += __shfl_down(la[c], off);
  if (lane == 0)
    #pragma unroll
    for (int c = 0; c < 8; ++c) wred[wid][c] = la[c];
  __syncthreads();
  if (tid == 0) {
    float lg[8];
    #pragma unroll
    for (int c = 0; c < 8; ++c)
      lg[c] = wred[0][c] + wred[1][c] + wred[2][c] + wred[3][c] + b2[c];
    float mx = lg[0];
    #pragma unroll
    for (int c = 1; c < 8; ++c) mx = fmaxf(mx, lg[c]);
    float e[8], s = 0.f;
    #pragma unroll
    for (int c = 0; c < 8; ++c) { e[c] = expf(lg[c] - mx); s += e[c]; }
    #pragma unroll
    for (int c = 0; c < 8; ++c) {
      float a = e[c] / s;
      att[c] = a;
      attn_out[(size_t)b * 8 + c] = a;
    }
  }
  __syncthreads();
  #pragma unroll
  for (int it = 0; it < 16; ++it) {
    int idx = it * 256 + tid;
    float w = 0.f;
    #pragma unroll
    for (int c = 0; c < 8; ++c) w = fmaf(att[c], wc[c * 4096 + idx], w);
    int s = idx & 15, q = (idx >> 4) & 15, p = idx >> 8;
    W123[idx][0] = w;                     // [p][q][s]
    W123[(q * 16 + s) * 16 + p][1] = w;   // [q][s][p]
    W123[(p * 16 + s) * 16 + q][2] = w;   // [p][s][q]
  }
  __syncthreads();

  const int so = tid & 15;
  const int i0 = tid >> 4, i1 = i0 + 16;
  float h0[16], r0[16], t0[16], h1[16], r1[16], t1[16];
  #pragma unroll
  for (int k = 0; k < 16; ++k) {
    h0[k] = hs[i0 * 16 + k]; r0[k] = rs[i0 * 16 + k]; t0[k] = ts[i0 * 16 + k];
    h1[k] = hs[i1 * 16 + k]; r1[k] = rs[i1 * 16 + k]; t1[k] = ts[i1 * 16 + k];
  }
  float a10 = 0.f, a20 = 0.f, a30 = 0.f, a11 = 0.f, a21 = 0.f, a31 = 0.f;
  const float4* wp = (const float4*)&W123[so][0];   // per-thread base
  #pragma unroll
  for (int u = 0; u < 16; ++u) {
    #pragma unroll
    for (int v = 0; v < 16; ++v) {
      float4 w = wp[u * 256 + v * 16];   // byte off = u*4096+v*256 (imm)
      a10 = fmaf(h0[u] * r0[v], w.x, a10);
      a20 = fmaf(r0[u] * t0[v], w.y, a20);
      a30 = fmaf(h0[u] * t0[v], w.z, a30);
      a11 = fmaf(h1[u] * r1[v], w.x, a11);
      a21 = fmaf(r1[u] * t1[v], w.y, a21);
      a31 = fmaf(h1[u] * t1[v], w.z, a31);
    }
  }
  x1b[(size_t)b * 512 + i0 * 16 + so] = f2bf(a10);
  x1b[(size_t)b * 512 + i1 * 16 + so] = f2bf(a11);
  red[tid] = a10 * a10 + a20 * a20 + a30 * a30
           + a11 * a11 + a21 * a21 + a31 * a31;
  __syncthreads();
  for (int s = 128; s > 0; s >>= 1) {
    if (tid < s) red[tid] += red[tid + s];
    __syncthreads();
  }
  if (tid == 0) n2[b] = red[0];
}

// ---------------------------------------------------------------------------
// K5: factors. factor1 = sum(n1)/B; factor2 = sum(n2)/B; factor3 geometric.
// ---------------------------------------------------------------------------
__global__ __launch_bounds__(256)
void finalize(const float* __restrict__ n1, const float* __restrict__ n2,
              const float* __restrict__ wc, float* __restrict__ out) {
  int tid = threadIdx.x;
  __shared__ float red[256];
  float a = 0.f;
  for (int i = tid; i < NB; i += 256) a += n1[i];
  red[tid] = a; __syncthreads();
  for (int s = 128; s > 0; s >>= 1) { if (tid < s) red[tid] += red[tid + s]; __syncthreads(); }
  if (tid == 0) out[F1_OFF] = red[0] / (float)NB;
  __syncthreads();
  a = 0.f;
  for (int i = tid; i < NB; i += 256) a += n2[i];
  red[tid] = a; __syncthreads();
  for (int s = 128; s > 0; s >>= 1) { if (tid < s) red[tid] += red[tid + s]; __syncthreads(); }
  if (tid == 0) out[F2_OFF] = red[0] / (float)NB;
  __syncthreads();

  // factor3: 32 lanes per core
  int c = tid >> 5, l = tid & 31;
  float tot = 0.f, cx = 0.f, cy = 0.f, cz = 0.f;
  for (int e = l; e < 4096; e += 32) {
    float w = fabsf(wc[c * 4096 + e]);
    int z = e & 15, y = (e >> 4) & 15, x = e >> 8;
    tot += w; cx += w * x; cy += w * y; cz += w * z;
  }
  #pragma unroll
  for (int off = 16; off > 0; off >>= 1) {
    tot += __shfl_down(tot, off);
    cx += __shfl_down(cx, off);
    cy += __shfl_down(cy, off);
    cz += __shfl_down(cz, off);
  }
  __shared__ float cent[8][3];
  if (l == 0) { cent[c][0] = cx / tot; cent[c][1] = cy / tot; cent[c][2] = cz / tot; }
  __syncthreads();
  if (tid == 0) {
    float f3 = 0.f;
    for (int i = 0; i < 8; ++i) {
      float mn = 1e30f;
      for (int j = 0; j < 8; ++j) {
        if (j == i) continue;
        float dx = cent[i][0] - cent[j][0];
        float dy = cent[i][1] - cent[j][1];
        float dz = cent[i][2] - cent[j][2];
        float d = sqrtf(dx * dx + dy * dy + dz * dz);
        mn = fminf(mn, d);
      }
      f3 += logf(mn + 1e-6f);
    }
    out[F3_OFF] = -f3 / 8.f;
  }
}

// ---------------------------------------------------------------------------
extern "C" void kernel_launch(void* const* d_in, const int* in_sizes, int n_in,
                              void* d_out, int out_size, void* d_ws, size_t ws_size,
                              hipStream_t stream) {
  const int* heads = (const int*)d_in[0];
  const int* rels = (const int*)d_in[1];
  const int* tails = (const int*)d_in[2];
  const float* ew = (const float*)d_in[3];
  const float* rw = (const float*)d_in[4];
  const float* wc = (const float*)d_in[5];
  const float* w1 = (const float*)d_in[6];
  const float* b1 = (const float*)d_in[7];
  const float* w2 = (const float*)d_in[8];
  const float* b2 = (const float*)d_in[9];
  float* out = (float*)d_out;

  uint8_t* ws = (uint8_t*)d_ws;
  const size_t EWB_SZ = (size_t)NE_PAD * DCOL * 2;   // 51,249,152
  unsigned short* ewb = (unsigned short*)ws;
  unsigned short* hrb = (unsigned short*)(ws + EWB_SZ);
  unsigned short* w1t = (unsigned short*)(ws + EWB_SZ + 2097152);
  float* hid = (float*)(ws + EWB_SZ + 2097152 + 1048576);
  unsigned short* x1b = (unsigned short*)(ws + EWB_SZ + 2097152 + 1048576 + 2097152);
  float* n1 = (float*)(ws + EWB_SZ + 2097152 + 1048576 + 2097152 + 1048576);
  float* n2 = n1 + NB;

  prep<<<NB + 512 + 2048, 256, 0, stream>>>(heads, rels, tails, ew, rw, w1,
                                            hrb, w1t, ewb, n1);
  // MLP GEMM: M=1024 (MT=16, BM=64), N=512 (NT=8), K=1024
  gemm_nt<1, 2, 0, 16><<<128, 256, 0, stream>>>(
      hrb, w1t, hid, b1, 1024, 512, 8);
  triple_core<<<NB, 256, 0, stream>>>(heads, rels, tails, ew, rw, wc,
                                      hid, w2, b2, out + ATTN_OFF, x1b, n2);
  // scores GEMM: M=1024 (MT=8, BM=128), N-tiles=391, K=512, bf16 B
  gemm_nt<0, 4, 1, 8><<<3128, 256, 0, stream>>>(
      x1b, ewb, out, nullptr, 512, NE, 391);
  finalize<<<1, 256, 0, stream>>>(n1, n2, wc, out);
}